// Round 2
// baseline (725.835 us; speedup 1.0000x reference)
//
#include <hip/hip_runtime.h>

#define N_NODES 50000
#define N_EDGES 800000
#define CH 96
#define C4 24          // CH / 4 float4s per row
#define STEPS 10

// ---------- CSR build ----------

__global__ void count_deg(const int* __restrict__ ei, int* __restrict__ deg, int ne) {
    int e = blockIdx.x * blockDim.x + threadIdx.x;
    if (e < ne) {
        int d = ei[ne + e];   // dst row of edge_index (int32 per harness)
        if ((unsigned)d < (unsigned)N_NODES) atomicAdd(&deg[d], 1);
    }
}

__global__ void compute_dinv(const int* __restrict__ deg, float* __restrict__ dinv, int n) {
    int i = blockIdx.x * blockDim.x + threadIdx.x;
    if (i < n) {
        int d = deg[i];
        dinv[i] = (d > 0) ? (1.0f / sqrtf((float)d)) : 0.0f;
    }
}

// hierarchical exclusive scan of deg -> row_ptr (3 kernels, 256-wide chunks)
__global__ void scan1(const int* __restrict__ deg, int* __restrict__ row_ptr,
                      int* __restrict__ partials, int n) {
    __shared__ int sm[256];
    int i = blockIdx.x * 256 + threadIdx.x;
    int v = (i < n) ? deg[i] : 0;
    sm[threadIdx.x] = v;
    __syncthreads();
    for (int off = 1; off < 256; off <<= 1) {
        int t = (threadIdx.x >= off) ? sm[threadIdx.x - off] : 0;
        __syncthreads();
        sm[threadIdx.x] += t;
        __syncthreads();
    }
    if (i < n) row_ptr[i + 1] = sm[threadIdx.x];          // inclusive within chunk
    if (threadIdx.x == 255) partials[blockIdx.x] = sm[255];
}

__global__ void scan2(int* __restrict__ partials, int nb) {
    __shared__ int sm[256];
    int v = (threadIdx.x < nb) ? partials[threadIdx.x] : 0;
    sm[threadIdx.x] = v;
    __syncthreads();
    for (int off = 1; off < 256; off <<= 1) {
        int t = (threadIdx.x >= off) ? sm[threadIdx.x - off] : 0;
        __syncthreads();
        sm[threadIdx.x] += t;
        __syncthreads();
    }
    if (threadIdx.x < nb) partials[threadIdx.x] = sm[threadIdx.x] - v;  // exclusive
}

__global__ void scan3(int* __restrict__ row_ptr, const int* __restrict__ partials, int n) {
    int i = blockIdx.x * 256 + threadIdx.x;
    if (i < n) row_ptr[i + 1] += partials[blockIdx.x];
    if (i == 0) row_ptr[0] = 0;
}

__global__ void fill_csr(const int* __restrict__ ei, const int* __restrict__ row_ptr,
                         int* __restrict__ cursor, const float* __restrict__ dinv,
                         int* __restrict__ csr_src, float* __restrict__ csr_norm, int ne) {
    int e = blockIdx.x * blockDim.x + threadIdx.x;
    if (e < ne) {
        int s = ei[e];
        int d = ei[ne + e];
        if ((unsigned)s >= (unsigned)N_NODES || (unsigned)d >= (unsigned)N_NODES) return;
        int pos = row_ptr[d] + atomicAdd(&cursor[d], 1);
        csr_src[pos]  = s;
        csr_norm[pos] = dinv[s] * dinv[d];
    }
}

// ---------- propagation ----------

__global__ void init_out(const float* __restrict__ x, float* __restrict__ out,
                         const float* __restrict__ gamma, int n4) {
    int i = blockIdx.x * blockDim.x + threadIdx.x;
    if (i < n4) {
        float g = gamma[0];
        float4 v = ((const float4*)x)[i];
        ((float4*)out)[i] = make_float4(g * v.x, g * v.y, g * v.z, g * v.w);
    }
}

// one thread per (node, channel-quad); gathers over the node's in-edges.
__global__ __launch_bounds__(256) void prop(const float* __restrict__ h_in,
                                            float* __restrict__ h_out,
                                            float* __restrict__ out,
                                            const int* __restrict__ row_ptr,
                                            const int* __restrict__ csr_src,
                                            const float* __restrict__ csr_norm,
                                            const float* __restrict__ gamma, int k) {
    int g = blockIdx.x * blockDim.x + threadIdx.x;
    if (g >= N_NODES * C4) return;
    int node = g / C4;
    int c4   = g - node * C4;
    int beg = row_ptr[node];
    int end = row_ptr[node + 1];
    const float4* __restrict__ hin4 = (const float4*)h_in;
    float4 acc = make_float4(0.f, 0.f, 0.f, 0.f);
    for (int e = beg; e < end; ++e) {
        int   s = csr_src[e];
        float w = csr_norm[e];
        float4 hv = hin4[s * C4 + c4];
        acc.x = fmaf(w, hv.x, acc.x);
        acc.y = fmaf(w, hv.y, acc.y);
        acc.z = fmaf(w, hv.z, acc.z);
        acc.w = fmaf(w, hv.w, acc.w);
    }
    float gk = gamma[k + 1];
    ((float4*)h_out)[g] = acc;
    float4 o = ((float4*)out)[g];
    o.x = fmaf(gk, acc.x, o.x);
    o.y = fmaf(gk, acc.y, o.y);
    o.z = fmaf(gk, acc.z, o.z);
    o.w = fmaf(gk, acc.w, o.w);
    ((float4*)out)[g] = o;
}

// ---------- launch ----------

static inline size_t align_up(size_t v, size_t a) { return (v + a - 1) & ~(a - 1); }

extern "C" void kernel_launch(void* const* d_in, const int* in_sizes, int n_in,
                              void* d_out, int out_size, void* d_ws, size_t ws_size,
                              hipStream_t stream) {
    const float* x     = (const float*)d_in[0];
    const int*   ei    = (const int*)d_in[1];      // int32 per harness conversion
    const float* gamma = (const float*)d_in[2];
    float*       out   = (float*)d_out;

    const int n  = N_NODES;
    const int ne = N_EDGES;
    const int nblk_nodes = (n + 255) / 256;          // 196

    // workspace carve-up (256B aligned), total ~46.5 MB
    char*  ws  = (char*)d_ws;
    size_t off = 0;
    int*   deg      = (int*)(ws + off);   off = align_up(off + (size_t)n * 4, 256);
    int*   row_ptr  = (int*)(ws + off);   off = align_up(off + (size_t)(n + 1) * 4, 256);
    int*   cursor   = (int*)(ws + off);   off = align_up(off + (size_t)n * 4, 256);
    int*   partials = (int*)(ws + off);   off = align_up(off + (size_t)nblk_nodes * 4, 256);
    float* dinv     = (float*)(ws + off); off = align_up(off + (size_t)n * 4, 256);
    int*   csr_src  = (int*)(ws + off);   off = align_up(off + (size_t)ne * 4, 256);
    float* csr_norm = (float*)(ws + off); off = align_up(off + (size_t)ne * 4, 256);
    float* hA       = (float*)(ws + off); off = align_up(off + (size_t)n * CH * 4, 256);
    float* hB       = (float*)(ws + off); off = align_up(off + (size_t)n * CH * 4, 256);
    (void)ws_size;

    hipMemsetAsync(deg,    0, (size_t)n * 4, stream);
    hipMemsetAsync(cursor, 0, (size_t)n * 4, stream);

    const int nblk_edges = (ne + 255) / 256;         // 3125
    count_deg<<<nblk_edges, 256, 0, stream>>>(ei, deg, ne);
    compute_dinv<<<nblk_nodes, 256, 0, stream>>>(deg, dinv, n);

    scan1<<<nblk_nodes, 256, 0, stream>>>(deg, row_ptr, partials, n);
    scan2<<<1, 256, 0, stream>>>(partials, nblk_nodes);
    scan3<<<nblk_nodes, 256, 0, stream>>>(row_ptr, partials, n);

    fill_csr<<<nblk_edges, 256, 0, stream>>>(ei, row_ptr, cursor, dinv, csr_src, csr_norm, ne);

    const int n4 = n * C4;                            // 1.2M float4s
    const int nblk_n4 = (n4 + 255) / 256;             // 4688
    init_out<<<nblk_n4, 256, 0, stream>>>(x, out, gamma, n4);

    const float* hin = x;
    float* hout = hA;
    for (int k = 0; k < STEPS; ++k) {
        prop<<<nblk_n4, 256, 0, stream>>>(hin, hout, out, row_ptr, csr_src, csr_norm, gamma, k);
        hin  = hout;
        hout = (hout == hA) ? hB : hA;
    }
}

// Round 4
// 623.509 us; speedup vs baseline: 1.1641x; 1.1641x over previous
//
#include <hip/hip_runtime.h>

#define N_NODES 50000
#define N_EDGES 800000
#define CH 96
#define C4 24          // CH / 4 float4s per row
#define STEPS 10

typedef float f32x4 __attribute__((ext_vector_type(4)));   // native vec for nontemporal built-ins

// ---------- CSR build ----------

__global__ void count_deg(const int* __restrict__ ei, int* __restrict__ deg, int ne) {
    int e = blockIdx.x * blockDim.x + threadIdx.x;
    if (e < ne) {
        int d = ei[ne + e];   // dst row of edge_index (int32 per harness)
        if ((unsigned)d < (unsigned)N_NODES) atomicAdd(&deg[d], 1);
    }
}

__global__ void compute_dinv(const int* __restrict__ deg, float* __restrict__ dinv, int n) {
    int i = blockIdx.x * blockDim.x + threadIdx.x;
    if (i < n) {
        int d = deg[i];
        dinv[i] = (d > 0) ? (1.0f / sqrtf((float)d)) : 0.0f;
    }
}

// hierarchical exclusive scan of deg -> row_ptr (3 kernels, 256-wide chunks)
__global__ void scan1(const int* __restrict__ deg, int* __restrict__ row_ptr,
                      int* __restrict__ partials, int n) {
    __shared__ int sm[256];
    int i = blockIdx.x * 256 + threadIdx.x;
    int v = (i < n) ? deg[i] : 0;
    sm[threadIdx.x] = v;
    __syncthreads();
    for (int off = 1; off < 256; off <<= 1) {
        int t = (threadIdx.x >= off) ? sm[threadIdx.x - off] : 0;
        __syncthreads();
        sm[threadIdx.x] += t;
        __syncthreads();
    }
    if (i < n) row_ptr[i + 1] = sm[threadIdx.x];          // inclusive within chunk
    if (threadIdx.x == 255) partials[blockIdx.x] = sm[255];
}

__global__ void scan2(int* __restrict__ partials, int nb) {
    __shared__ int sm[256];
    int v = (threadIdx.x < nb) ? partials[threadIdx.x] : 0;
    sm[threadIdx.x] = v;
    __syncthreads();
    for (int off = 1; off < 256; off <<= 1) {
        int t = (threadIdx.x >= off) ? sm[threadIdx.x - off] : 0;
        __syncthreads();
        sm[threadIdx.x] += t;
        __syncthreads();
    }
    if (threadIdx.x < nb) partials[threadIdx.x] = sm[threadIdx.x] - v;  // exclusive
}

__global__ void scan3(int* __restrict__ row_ptr, const int* __restrict__ partials, int n) {
    int i = blockIdx.x * 256 + threadIdx.x;
    if (i < n) row_ptr[i + 1] += partials[blockIdx.x];
    if (i == 0) row_ptr[0] = 0;
}

// packed CSR entry: .x = src index, .y = float bits of norm  (one 8B store/edge)
__global__ void fill_csr(const int* __restrict__ ei, const int* __restrict__ row_ptr,
                         int* __restrict__ cursor, const float* __restrict__ dinv,
                         int2* __restrict__ csr_pack, int ne) {
    int e = blockIdx.x * blockDim.x + threadIdx.x;
    if (e < ne) {
        int s = ei[e];
        int d = ei[ne + e];
        if ((unsigned)s >= (unsigned)N_NODES || (unsigned)d >= (unsigned)N_NODES) return;
        int pos = row_ptr[d] + atomicAdd(&cursor[d], 1);
        csr_pack[pos] = make_int2(s, __float_as_int(dinv[s] * dinv[d]));
    }
}

// ---------- propagation ----------
// one thread per (node, channel-quad); edge loop unrolled x4 with 4 independent
// accumulators -> 4 outstanding random gathers per thread (latency hiding).
// k==0 also computes out = gamma0*x + gamma1*acc (init_out fused).
// k==STEPS-1 skips the h_out write.
__global__ __launch_bounds__(256) void prop(const float* __restrict__ h_in,
                                            float* __restrict__ h_out,
                                            float* __restrict__ out,
                                            const int* __restrict__ row_ptr,
                                            const int2* __restrict__ csr_pack,
                                            const float* __restrict__ gamma, int k) {
    int g = blockIdx.x * blockDim.x + threadIdx.x;
    if (g >= N_NODES * C4) return;
    int node = g / C4;
    int c4   = g - node * C4;
    int beg = row_ptr[node];
    int end = row_ptr[node + 1];
    const float4* __restrict__ hin4 = (const float4*)h_in;

    float4 a0 = make_float4(0.f, 0.f, 0.f, 0.f);
    float4 a1 = a0, a2 = a0, a3 = a0;

    int e = beg;
    for (; e + 4 <= end; e += 4) {
        int2 m0 = csr_pack[e];
        int2 m1 = csr_pack[e + 1];
        int2 m2 = csr_pack[e + 2];
        int2 m3 = csr_pack[e + 3];
        float4 h0 = hin4[m0.x * C4 + c4];
        float4 h1 = hin4[m1.x * C4 + c4];
        float4 h2 = hin4[m2.x * C4 + c4];
        float4 h3 = hin4[m3.x * C4 + c4];
        float w0 = __int_as_float(m0.y), w1 = __int_as_float(m1.y);
        float w2 = __int_as_float(m2.y), w3 = __int_as_float(m3.y);
        a0.x = fmaf(w0, h0.x, a0.x); a0.y = fmaf(w0, h0.y, a0.y);
        a0.z = fmaf(w0, h0.z, a0.z); a0.w = fmaf(w0, h0.w, a0.w);
        a1.x = fmaf(w1, h1.x, a1.x); a1.y = fmaf(w1, h1.y, a1.y);
        a1.z = fmaf(w1, h1.z, a1.z); a1.w = fmaf(w1, h1.w, a1.w);
        a2.x = fmaf(w2, h2.x, a2.x); a2.y = fmaf(w2, h2.y, a2.y);
        a2.z = fmaf(w2, h2.z, a2.z); a2.w = fmaf(w2, h2.w, a2.w);
        a3.x = fmaf(w3, h3.x, a3.x); a3.y = fmaf(w3, h3.y, a3.y);
        a3.z = fmaf(w3, h3.z, a3.z); a3.w = fmaf(w3, h3.w, a3.w);
    }
    for (; e < end; ++e) {
        int2 m = csr_pack[e];
        float4 hv = hin4[m.x * C4 + c4];
        float w = __int_as_float(m.y);
        a0.x = fmaf(w, hv.x, a0.x); a0.y = fmaf(w, hv.y, a0.y);
        a0.z = fmaf(w, hv.z, a0.z); a0.w = fmaf(w, hv.w, a0.w);
    }
    float4 acc;
    acc.x = (a0.x + a1.x) + (a2.x + a3.x);
    acc.y = (a0.y + a1.y) + (a2.y + a3.y);
    acc.z = (a0.z + a1.z) + (a2.z + a3.z);
    acc.w = (a0.w + a1.w) + (a2.w + a3.w);

    float gk = gamma[k + 1];
    float4 o;
    if (k == 0) {
        float g0 = gamma[0];
        float4 xo = hin4[g];          // h_in == x at k==0
        o.x = fmaf(gk, acc.x, g0 * xo.x);
        o.y = fmaf(gk, acc.y, g0 * xo.y);
        o.z = fmaf(gk, acc.z, g0 * xo.z);
        o.w = fmaf(gk, acc.w, g0 * xo.w);
    } else {
        o = ((float4*)out)[g];
        o.x = fmaf(gk, acc.x, o.x);
        o.y = fmaf(gk, acc.y, o.y);
        o.z = fmaf(gk, acc.z, o.z);
        o.w = fmaf(gk, acc.w, o.w);
    }
    ((float4*)out)[g] = o;
    if (k != STEPS - 1) {
        // next step reads this from a mostly-remote XCD: don't pollute local L2
        f32x4 accv = { acc.x, acc.y, acc.z, acc.w };
        __builtin_nontemporal_store(accv, &((f32x4*)h_out)[g]);
    }
}

// ---------- launch ----------

static inline size_t align_up(size_t v, size_t a) { return (v + a - 1) & ~(a - 1); }

extern "C" void kernel_launch(void* const* d_in, const int* in_sizes, int n_in,
                              void* d_out, int out_size, void* d_ws, size_t ws_size,
                              hipStream_t stream) {
    const float* x     = (const float*)d_in[0];
    const int*   ei    = (const int*)d_in[1];      // int32 per harness conversion
    const float* gamma = (const float*)d_in[2];
    float*       out   = (float*)d_out;

    const int n  = N_NODES;
    const int ne = N_EDGES;
    const int nblk_nodes = (n + 255) / 256;          // 196

    // workspace carve-up (256B aligned), total ~46 MB
    char*  ws  = (char*)d_ws;
    size_t off = 0;
    int*   deg      = (int*)(ws + off);   off = align_up(off + (size_t)n * 4, 256);
    int*   row_ptr  = (int*)(ws + off);   off = align_up(off + (size_t)(n + 1) * 4, 256);
    int*   cursor   = (int*)(ws + off);   off = align_up(off + (size_t)n * 4, 256);
    int*   partials = (int*)(ws + off);   off = align_up(off + (size_t)nblk_nodes * 4, 256);
    float* dinv     = (float*)(ws + off); off = align_up(off + (size_t)n * 4, 256);
    int2*  csr_pack = (int2*)(ws + off);  off = align_up(off + (size_t)ne * 8, 256);
    float* hA       = (float*)(ws + off); off = align_up(off + (size_t)n * CH * 4, 256);
    float* hB       = (float*)(ws + off); off = align_up(off + (size_t)n * CH * 4, 256);
    (void)ws_size;

    (void)hipMemsetAsync(deg,    0, (size_t)n * 4, stream);
    (void)hipMemsetAsync(cursor, 0, (size_t)n * 4, stream);

    const int nblk_edges = (ne + 255) / 256;         // 3125
    count_deg<<<nblk_edges, 256, 0, stream>>>(ei, deg, ne);
    compute_dinv<<<nblk_nodes, 256, 0, stream>>>(deg, dinv, n);

    scan1<<<nblk_nodes, 256, 0, stream>>>(deg, row_ptr, partials, n);
    scan2<<<1, 256, 0, stream>>>(partials, nblk_nodes);
    scan3<<<nblk_nodes, 256, 0, stream>>>(row_ptr, partials, n);

    fill_csr<<<nblk_edges, 256, 0, stream>>>(ei, row_ptr, cursor, dinv, csr_pack, ne);

    const int n4 = n * C4;                            // 1.2M float4s
    const int nblk_n4 = (n4 + 255) / 256;             // 4688

    const float* hin = x;
    float* hout = hA;
    for (int k = 0; k < STEPS; ++k) {
        prop<<<nblk_n4, 256, 0, stream>>>(hin, hout, out, row_ptr, csr_pack, gamma, k);
        hin  = hout;
        hout = (hout == hA) ? hB : hA;
    }
}